// Round 3
// baseline (97.158 us; speedup 1.0000x reference)
//
#include <hip/hip_runtime.h>

// Problem constants (fixed by setup_inputs)
namespace {
constexpr int BB = 4;
constexpr int CC = 19;
constexpr int HH = 256;
constexpr int WW = 256;
constexpr int HW = HH * WW;        // 65536
constexpr int NPIX = BB * HW;      // 262144
constexpr int BIGI = 512;          // H + W, the reference's "big" sentinel
}

// Kernel A: per-pixel softmax, argmax, masks, and S = sum_{c>=1} (p_c - t)^2.
// All reads/writes fully coalesced. Also zeroes the last-block counter.
__global__ __launch_bounds__(256) void softmax_pixel_kernel(
    const float* __restrict__ pred, const int* __restrict__ target,
    float* __restrict__ S, unsigned char* __restrict__ mask,
    unsigned int* __restrict__ counter)
{
    int idx = blockIdx.x * 256 + threadIdx.x;   // grid exactly covers NPIX
    if (idx == 0) counter[0] = 0u;              // for kernel C's last-block reduce
    int b = idx >> 16;                          // / HW
    int pix = idx & (HW - 1);
    const float* p = pred + (size_t)b * CC * HW + pix;

    float x[CC];
#pragma unroll
    for (int c = 0; c < CC; ++c) x[c] = p[(size_t)c * HW];

    float m = x[0]; int am = 0;
#pragma unroll
    for (int c = 1; c < CC; ++c) { if (x[c] > m) { m = x[c]; am = c; } }

    float Z = 0.f;
#pragma unroll
    for (int c = 0; c < CC; ++c) { x[c] = __expf(x[c] - m); Z += x[c]; }
    float inv = 1.0f / Z;

    int t = target[idx];
    if (t == 255) t = 0;                        // IGNORE_INDEX -> class 0
    float tf = (float)t;

    float s = 0.f;
#pragma unroll
    for (int c = 1; c < CC; ++c) {              // classes 1..C-1 only
        float pc = x[c] * inv;                  // match reference rounding order
        float d = pc - tf;
        s = fmaf(d, d, s);
    }
    S[idx] = s;
    // bit0: gt foreground (tgt != 0); bit1: seg foreground (argmax != 0)
    mask[idx] = (unsigned char)((t != 0 ? 1 : 0) | (am != 0 ? 2 : 0));
}

// Kernel B: vertical EDT pass (phase 1) as a wave-parallel max-scan.
// One 64-lane wave per column; lane l owns rows 4l..4l+3. All-integer (exact).
// Reference sentinel semantics preserved exactly:
//   up = i - prefixmax(zero ? i : -512)    (i+512 if no zero above)
//   dn = -suffixmax(zero ? -i : -512) - i  (512-i if no zero below)
//   g = min(up, dn, 512)
// Output: packed (g_gt | g_seg<<16) per pixel, TRANSPOSED (b, w, h) layout,
// written as one coalesced uint4 per lane.
__global__ __launch_bounds__(256) void edt_vertical_kernel(
    const unsigned char* __restrict__ mask,
    unsigned int* __restrict__ gpk_t)
{
    int wave = threadIdx.x >> 6;
    int lane = threadIdx.x & 63;
    int col = blockIdx.x * 4 + wave;            // 0 .. BB*WW-1
    int b = col >> 8;
    int w = col & (WW - 1);
    int r0 = lane << 2;                         // first row this lane owns

    const unsigned char* mcol = mask + ((size_t)b << 16) + w;
    unsigned char mq[4];
#pragma unroll
    for (int q = 0; q < 4; ++q) mq[q] = mcol[(size_t)(r0 + q) << 8];  // strided, L2/L3-served

    int pu_g[4], pu_s[4], pd_g[4], pd_s[4];
#pragma unroll
    for (int q = 0; q < 4; ++q) {
        int r = r0 + q;
        bool zg = !(mq[q] & 1), zs = !(mq[q] & 2);
        pu_g[q] = zg ?  r : -BIGI;
        pu_s[q] = zs ?  r : -BIGI;
        pd_g[q] = zg ? -r : -BIGI;
        pd_s[q] = zs ? -r : -BIGI;
    }
    // lane-local inclusive prefix max (up) and suffix max (down)
#pragma unroll
    for (int q = 1; q < 4; ++q) {
        pu_g[q] = max(pu_g[q], pu_g[q - 1]);
        pu_s[q] = max(pu_s[q], pu_s[q - 1]);
    }
#pragma unroll
    for (int q = 2; q >= 0; --q) {
        pd_g[q] = max(pd_g[q], pd_g[q + 1]);
        pd_s[q] = max(pd_s[q], pd_s[q + 1]);
    }

    // wave-level scans of lane carries
    int cu_g = pu_g[3], cu_s = pu_s[3];         // prefix carries
    int cd_g = pd_g[0], cd_s = pd_s[0];         // suffix carries
#pragma unroll
    for (int d = 1; d < 64; d <<= 1) {
        int t;
        t = __shfl_up(cu_g, d, 64);   if (lane >= d)     cu_g = max(cu_g, t);
        t = __shfl_up(cu_s, d, 64);   if (lane >= d)     cu_s = max(cu_s, t);
        t = __shfl_down(cd_g, d, 64); if (lane + d < 64) cd_g = max(cd_g, t);
        t = __shfl_down(cd_s, d, 64); if (lane + d < 64) cd_s = max(cd_s, t);
    }
    // exclusive neighbors
    int eu_g = __shfl_up(cu_g, 1, 64);   if (lane == 0)  eu_g = -BIGI;
    int eu_s = __shfl_up(cu_s, 1, 64);   if (lane == 0)  eu_s = -BIGI;
    int ed_g = __shfl_down(cd_g, 1, 64); if (lane == 63) ed_g = -BIGI;
    int ed_s = __shfl_down(cd_s, 1, 64); if (lane == 63) ed_s = -BIGI;

    uint4 outv;
    unsigned int* ov = (unsigned int*)&outv;
#pragma unroll
    for (int q = 0; q < 4; ++q) {
        int r = r0 + q;
        int up_g = r - max(pu_g[q], eu_g);
        int up_s = r - max(pu_s[q], eu_s);
        int dn_g = -max(pd_g[q], ed_g) - r;
        int dn_s = -max(pd_s[q], ed_s) - r;
        int gg = min(min(up_g, dn_g), BIGI);
        int gs = min(min(up_s, dn_s), BIGI);
        ov[q] = (unsigned int)gg | ((unsigned int)gs << 16);
    }
    // (b, w, h) layout: lane's 4 rows are contiguous -> coalesced uint4
    *(uint4*)(gpk_t + ((size_t)col << 8) + r0) = outv;
}

// Kernel C: horizontal EDT (phase 2) fused with the weighted reduction and
// (last block) the final scalar reduce. One block per row (b,h), 256 threads.
// Inner loop uses g^2+(j-jp)^2 = (g^2+jp^2) - 2j*jp + j^2: stage q=g^2+jp^2
// once, then fma+min3 per candidate. All values integer-exact in fp32.
__global__ __launch_bounds__(256) void edt_horiz_reduce_kernel(
    const unsigned int* __restrict__ gpk_t, const float* __restrict__ S,
    double* __restrict__ partial, unsigned int* __restrict__ counter,
    float* __restrict__ out)
{
    __shared__ __align__(16) float lgq[WW];     // g_gt^2 + jp^2
    __shared__ __align__(16) float lsq[WW];     // g_seg^2 + jp^2
    int r = blockIdx.x;                         // 0 .. BB*HH-1
    int b = r >> 8;
    int h = r & (HH - 1);
    int j = threadIdx.x;

    // strided gather from (b,w,h) layout — L2/L3-resident
    unsigned int pk = gpk_t[((size_t)b << 16) + ((size_t)j << 8) + h];
    int gg = (int)(pk & 0xffffu);
    int gs = (int)(pk >> 16);
    lgq[j] = (float)(gg * gg + j * j);
    lsq[j] = (float)(gs * gs + j * j);
    __syncthreads();

    float ntj = -2.0f * (float)j;
    float f0 = 0.f, f1 = 1.f, f2 = 2.f, f3 = 3.f;
    float ag0 = 1e30f, ag1 = 1e30f, as0 = 1e30f, as1 = 1e30f;
    const float4* lg4 = (const float4*)lgq;
    const float4* ls4 = (const float4*)lsq;
#pragma unroll 8
    for (int i = 0; i < WW / 4; ++i) {
        float4 qg = lg4[i];                     // LDS broadcast: conflict-free
        float4 qs = ls4[i];
        ag0 = fminf(fminf(fmaf(ntj, f0, qg.x), fmaf(ntj, f1, qg.y)), ag0);
        ag1 = fminf(fminf(fmaf(ntj, f2, qg.z), fmaf(ntj, f3, qg.w)), ag1);
        as0 = fminf(fminf(fmaf(ntj, f0, qs.x), fmaf(ntj, f1, qs.y)), as0);
        as1 = fminf(fminf(fmaf(ntj, f2, qs.z), fmaf(ntj, f3, qs.w)), as1);
        f0 += 4.f; f1 += 4.f; f2 += 4.f; f3 += 4.f;
    }
    float jj2 = (float)(j * j);
    float dtm2 = fminf(ag0, ag1) + fminf(as0, as1) + 2.f * jj2;  // seg^2+gt^2

    double v = (double)(dtm2 * S[((size_t)r << 8) + j]);

    // deterministic block reduction
    for (int k = 32; k >= 1; k >>= 1) v += __shfl_down(v, k, 64);
    __shared__ double wsum[4];
    __shared__ bool isLast;
    int wv = threadIdx.x >> 6;
    if ((threadIdx.x & 63) == 0) wsum[wv] = v;
    __syncthreads();
    if (threadIdx.x == 0) {
        partial[r] = wsum[0] + wsum[1] + wsum[2] + wsum[3];
        __threadfence();                        // release partial[r]
        unsigned int old = atomicAdd(counter, 1u);
        isLast = (old == (unsigned int)(BB * HH - 1));
    }
    __syncthreads();
    if (isLast) {
        __threadfence();                        // acquire all partial[]
        double t = 0.0;
        for (int i = threadIdx.x; i < BB * HH; i += 256) t += partial[i];
        for (int k = 32; k >= 1; k >>= 1) t += __shfl_down(t, k, 64);
        if ((threadIdx.x & 63) == 0) wsum[wv] = t;
        __syncthreads();
        if (threadIdx.x == 0) {
            double total = (wsum[0] + wsum[1] + wsum[2] + wsum[3])
                           / ((double)NPIX * (double)CC);
            out[0] = (float)total;              // LOSS_WEIGHT = 1
        }
    }
}

extern "C" void kernel_launch(void* const* d_in, const int* in_sizes, int n_in,
                              void* d_out, int out_size, void* d_ws, size_t ws_size,
                              hipStream_t stream) {
    const float* pred  = (const float*)d_in[0];
    const int* target  = (const int*)d_in[1];
    float* out = (float*)d_out;

    char* ws = (char*)d_ws;
    float* S              = (float*)(ws);                                   // 1 MiB
    unsigned char* mask   = (unsigned char*)(ws + (1u << 20));              // 256 KiB (b,h,w)
    unsigned int* gpk_t   = (unsigned int*)(ws + (1u << 20) + (1u << 18));  // 1 MiB (b,w,h)
    double* partial       = (double*)(ws + (2u << 20) + (1u << 18));        // 8 KiB
    unsigned int* counter = (unsigned int*)(ws + (2u << 20) + (1u << 18) + 8192);

    softmax_pixel_kernel<<<NPIX / 256, 256, 0, stream>>>(pred, target, S, mask, counter);
    edt_vertical_kernel<<<(BB * WW) / 4, 256, 0, stream>>>(mask, gpk_t);
    edt_horiz_reduce_kernel<<<BB * HH, 256, 0, stream>>>(gpk_t, S, partial, counter, out);
}

// Round 5
// 88.591 us; speedup vs baseline: 1.0967x; 1.0967x over previous
//
#include <hip/hip_runtime.h>

// Problem constants (fixed by setup_inputs)
namespace {
constexpr int BB = 4;
constexpr int CC = 19;
constexpr int HH = 256;
constexpr int WW = 256;
constexpr int HW = HH * WW;        // 65536
constexpr int NPIX = BB * HW;      // 262144
constexpr int BIGI = 512;          // H + W, the reference's "big" sentinel
}

// Kernel A: per-pixel softmax, argmax, masks, and S = sum_{c>=1} (p_c - t)^2.
// 2 pixels per thread via float2 (pix even -> aligned). Per-pixel arithmetic
// order identical to the bit-exact round-3 version.
__global__ __launch_bounds__(256) void softmax_pixel_kernel(
    const float* __restrict__ pred, const int* __restrict__ target,
    float* __restrict__ S, unsigned char* __restrict__ mask,
    unsigned int* __restrict__ counter)
{
    int tid = blockIdx.x * 256 + threadIdx.x;   // 0 .. NPIX/2-1
    if (tid == 0) counter[0] = 0u;              // for kernel C's last-block reduce
    int idx = tid << 1;
    int b = idx >> 16;                          // / HW
    int pix = idx & (HW - 1);
    const float* p = pred + (size_t)b * CC * HW + pix;

    float xa[CC], xb[CC];
#pragma unroll
    for (int c = 0; c < CC; ++c) {
        float2 v = *(const float2*)(p + (size_t)c * HW);
        xa[c] = v.x; xb[c] = v.y;
    }

    float ma = xa[0], mb = xb[0]; int ama = 0, amb = 0;
#pragma unroll
    for (int c = 1; c < CC; ++c) {
        if (xa[c] > ma) { ma = xa[c]; ama = c; }
        if (xb[c] > mb) { mb = xb[c]; amb = c; }
    }

    float Za = 0.f, Zb = 0.f;
#pragma unroll
    for (int c = 0; c < CC; ++c) {
        xa[c] = __expf(xa[c] - ma); Za += xa[c];
        xb[c] = __expf(xb[c] - mb); Zb += xb[c];
    }
    float inva = 1.0f / Za, invb = 1.0f / Zb;

    int2 t2 = *(const int2*)(target + idx);
    int ta = t2.x, tb = t2.y;
    if (ta == 255) ta = 0;                      // IGNORE_INDEX -> class 0
    if (tb == 255) tb = 0;
    float tfa = (float)ta, tfb = (float)tb;

    float sa = 0.f, sb = 0.f;
#pragma unroll
    for (int c = 1; c < CC; ++c) {              // classes 1..C-1 only
        float pa = xa[c] * inva;                // same rounding order as r3
        float da = pa - tfa;
        sa = fmaf(da, da, sa);
        float pb = xb[c] * invb;
        float db = pb - tfb;
        sb = fmaf(db, db, sb);
    }
    *(float2*)(S + idx) = make_float2(sa, sb);
    // bit0: gt foreground (tgt != 0); bit1: seg foreground (argmax != 0)
    unsigned short mp = (unsigned short)(((ta != 0 ? 1 : 0) | (ama != 0 ? 2 : 0))
                      | ((((tb != 0 ? 1 : 0) | (amb != 0 ? 2 : 0))) << 8));
    *(unsigned short*)(mask + idx) = mp;
}

// Kernel B: vertical EDT pass (phase 1) as a wave-parallel max-scan.
// One 64-lane wave per column; lane l owns rows 4l..4l+3. All-integer (exact).
// Reference sentinel semantics preserved exactly:
//   up = i - prefixmax(zero ? i : -512)    (i+512 if no zero above)
//   dn = -suffixmax(zero ? -i : -512) - i  (512-i if no zero below)
//   g = min(up, dn, 512)
// Output: packed (g_gt | g_seg<<16) per pixel, TRANSPOSED (b, w, h) layout,
// written as one coalesced uint4 per lane.
__global__ __launch_bounds__(256) void edt_vertical_kernel(
    const unsigned char* __restrict__ mask,
    unsigned int* __restrict__ gpk_t)
{
    int wave = threadIdx.x >> 6;
    int lane = threadIdx.x & 63;
    int col = blockIdx.x * 4 + wave;            // 0 .. BB*WW-1
    int b = col >> 8;
    int w = col & (WW - 1);
    int r0 = lane << 2;                         // first row this lane owns

    const unsigned char* mcol = mask + ((size_t)b << 16) + w;
    unsigned char mq[4];
#pragma unroll
    for (int q = 0; q < 4; ++q) mq[q] = mcol[(size_t)(r0 + q) << 8];  // strided, L2-served

    int pu_g[4], pu_s[4], pd_g[4], pd_s[4];
#pragma unroll
    for (int q = 0; q < 4; ++q) {
        int r = r0 + q;
        bool zg = !(mq[q] & 1), zs = !(mq[q] & 2);
        pu_g[q] = zg ?  r : -BIGI;
        pu_s[q] = zs ?  r : -BIGI;
        pd_g[q] = zg ? -r : -BIGI;
        pd_s[q] = zs ? -r : -BIGI;
    }
    // lane-local inclusive prefix max (up) and suffix max (down)
#pragma unroll
    for (int q = 1; q < 4; ++q) {
        pu_g[q] = max(pu_g[q], pu_g[q - 1]);
        pu_s[q] = max(pu_s[q], pu_s[q - 1]);
    }
#pragma unroll
    for (int q = 2; q >= 0; --q) {
        pd_g[q] = max(pd_g[q], pd_g[q + 1]);
        pd_s[q] = max(pd_s[q], pd_s[q + 1]);
    }

    // wave-level scans of lane carries
    int cu_g = pu_g[3], cu_s = pu_s[3];         // prefix carries
    int cd_g = pd_g[0], cd_s = pd_s[0];         // suffix carries
#pragma unroll
    for (int d = 1; d < 64; d <<= 1) {
        int t;
        t = __shfl_up(cu_g, d, 64);   if (lane >= d)     cu_g = max(cu_g, t);
        t = __shfl_up(cu_s, d, 64);   if (lane >= d)     cu_s = max(cu_s, t);
        t = __shfl_down(cd_g, d, 64); if (lane + d < 64) cd_g = max(cd_g, t);
        t = __shfl_down(cd_s, d, 64); if (lane + d < 64) cd_s = max(cd_s, t);
    }
    // exclusive neighbors
    int eu_g = __shfl_up(cu_g, 1, 64);   if (lane == 0)  eu_g = -BIGI;
    int eu_s = __shfl_up(cu_s, 1, 64);   if (lane == 0)  eu_s = -BIGI;
    int ed_g = __shfl_down(cd_g, 1, 64); if (lane == 63) ed_g = -BIGI;
    int ed_s = __shfl_down(cd_s, 1, 64); if (lane == 63) ed_s = -BIGI;

    uint4 outv;
    unsigned int* ov = (unsigned int*)&outv;
#pragma unroll
    for (int q = 0; q < 4; ++q) {
        int r = r0 + q;
        int up_g = r - max(pu_g[q], eu_g);
        int up_s = r - max(pu_s[q], eu_s);
        int dn_g = -max(pd_g[q], ed_g) - r;
        int dn_s = -max(pd_s[q], ed_s) - r;
        int gg = min(min(up_g, dn_g), BIGI);
        int gs = min(min(up_s, dn_s), BIGI);
        ov[q] = (unsigned int)gg | ((unsigned int)gs << 16);
    }
    // (b, w, h) layout: lane's 4 rows are contiguous -> coalesced uint4
    *(uint4*)(gpk_t + ((size_t)col << 8) + r0) = outv;
}

// Kernel C: horizontal EDT (phase 2) fused with the weighted reduction and
// (last block) the final scalar reduce. TWO rows (b, h0=2k, h1=2k+1) per
// block, 256 threads = one j each. Inner loop uses
// g^2+(j-jp)^2 = (g^2+jp^2) - 2j*jp + j^2 -> fma+min3 per candidate; the
// jp-counter registers are amortized over both rows. Integer-exact in fp32.
__global__ __launch_bounds__(256) void edt_horiz_reduce_kernel(
    const unsigned int* __restrict__ gpk_t, const float* __restrict__ S,
    double* __restrict__ partial, unsigned int* __restrict__ counter,
    float* __restrict__ out)
{
    __shared__ __align__(16) float lgq0[WW], lsq0[WW], lgq1[WW], lsq1[WW];
    int rp = blockIdx.x;                        // 0 .. BB*HH/2-1
    int r0 = rp << 1;                           // rows r0, r0+1 (same b)
    int b = r0 >> 8;
    int h0 = r0 & (HH - 1);
    int j = threadIdx.x;

    // gather both rows' packed g from (b,w,h) layout in one uint2 (h0 even)
    uint2 pk2 = *(const uint2*)(gpk_t + ((size_t)b << 16) + ((size_t)j << 8) + h0);
    int jj = j * j;
    {
        int gg = (int)(pk2.x & 0xffffu), gs = (int)(pk2.x >> 16);
        lgq0[j] = (float)(gg * gg + jj);
        lsq0[j] = (float)(gs * gs + jj);
        gg = (int)(pk2.y & 0xffffu); gs = (int)(pk2.y >> 16);
        lgq1[j] = (float)(gg * gg + jj);
        lsq1[j] = (float)(gs * gs + jj);
    }
    __syncthreads();

    float ntj = -2.0f * (float)j;
    float f0 = 0.f, f1 = 1.f, f2 = 2.f, f3 = 3.f;
    float ag0 = 1e30f, ag1 = 1e30f, as0 = 1e30f, as1 = 1e30f;
    float bg0 = 1e30f, bg1 = 1e30f, bs0 = 1e30f, bs1 = 1e30f;
    const float4* g40 = (const float4*)lgq0;
    const float4* s40 = (const float4*)lsq0;
    const float4* g41 = (const float4*)lgq1;
    const float4* s41 = (const float4*)lsq1;
#pragma unroll 8
    for (int i = 0; i < WW / 4; ++i) {
        float4 qg0 = g40[i], qs0 = s40[i];      // LDS broadcast: conflict-free
        float4 qg1 = g41[i], qs1 = s41[i];
        ag0 = fminf(fminf(fmaf(ntj, f0, qg0.x), fmaf(ntj, f1, qg0.y)), ag0);
        ag1 = fminf(fminf(fmaf(ntj, f2, qg0.z), fmaf(ntj, f3, qg0.w)), ag1);
        as0 = fminf(fminf(fmaf(ntj, f0, qs0.x), fmaf(ntj, f1, qs0.y)), as0);
        as1 = fminf(fminf(fmaf(ntj, f2, qs0.z), fmaf(ntj, f3, qs0.w)), as1);
        bg0 = fminf(fminf(fmaf(ntj, f0, qg1.x), fmaf(ntj, f1, qg1.y)), bg0);
        bg1 = fminf(fminf(fmaf(ntj, f2, qg1.z), fmaf(ntj, f3, qg1.w)), bg1);
        bs0 = fminf(fminf(fmaf(ntj, f0, qs1.x), fmaf(ntj, f1, qs1.y)), bs0);
        bs1 = fminf(fminf(fmaf(ntj, f2, qs1.z), fmaf(ntj, f3, qs1.w)), bs1);
        f0 += 4.f; f1 += 4.f; f2 += 4.f; f3 += 4.f;
    }
    float jj2x2 = 2.f * (float)jj;
    float dtm2_0 = fminf(ag0, ag1) + fminf(as0, as1) + jj2x2;  // seg^2+gt^2, row0
    float dtm2_1 = fminf(bg0, bg1) + fminf(bs0, bs1) + jj2x2;  // row1

    double v = (double)(dtm2_0 * S[((size_t)r0 << 8) + j])
             + (double)(dtm2_1 * S[((size_t)(r0 + 1) << 8) + j]);

    // deterministic block reduction
    for (int k = 32; k >= 1; k >>= 1) v += __shfl_down(v, k, 64);
    __shared__ double wsum[4];
    __shared__ bool isLast;
    int wv = threadIdx.x >> 6;
    if ((threadIdx.x & 63) == 0) wsum[wv] = v;
    __syncthreads();
    if (threadIdx.x == 0) {
        partial[rp] = wsum[0] + wsum[1] + wsum[2] + wsum[3];
        __threadfence();                        // release partial[rp]
        unsigned int old = atomicAdd(counter, 1u);
        isLast = (old == (unsigned int)(BB * HH / 2 - 1));
    }
    __syncthreads();
    if (isLast) {
        __threadfence();                        // acquire all partial[] (L2 inv)
        double t = 0.0;
        for (int i = threadIdx.x; i < BB * HH / 2; i += 256) t += partial[i];
        for (int k = 32; k >= 1; k >>= 1) t += __shfl_down(t, k, 64);
        if ((threadIdx.x & 63) == 0) wsum[wv] = t;
        __syncthreads();
        if (threadIdx.x == 0) {
            double total = (wsum[0] + wsum[1] + wsum[2] + wsum[3])
                           / ((double)NPIX * (double)CC);
            out[0] = (float)total;              // LOSS_WEIGHT = 1
        }
    }
}

extern "C" void kernel_launch(void* const* d_in, const int* in_sizes, int n_in,
                              void* d_out, int out_size, void* d_ws, size_t ws_size,
                              hipStream_t stream) {
    const float* pred  = (const float*)d_in[0];
    const int* target  = (const int*)d_in[1];
    float* out = (float*)d_out;

    char* ws = (char*)d_ws;
    float* S              = (float*)(ws);                                   // 1 MiB
    unsigned char* mask   = (unsigned char*)(ws + (1u << 20));              // 256 KiB (b,h,w)
    unsigned int* gpk_t   = (unsigned int*)(ws + (1u << 20) + (1u << 18));  // 1 MiB (b,w,h)
    double* partial       = (double*)(ws + (2u << 20) + (1u << 18));        // 4 KiB
    unsigned int* counter = (unsigned int*)(ws + (2u << 20) + (1u << 18) + 8192);

    softmax_pixel_kernel<<<NPIX / 512, 256, 0, stream>>>(pred, target, S, mask, counter);
    edt_vertical_kernel<<<(BB * WW) / 4, 256, 0, stream>>>(mask, gpk_t);
    edt_horiz_reduce_kernel<<<BB * HH / 2, 256, 0, stream>>>(gpk_t, S, partial, counter, out);
}